// Round 5
// baseline (292.993 us; speedup 1.0000x reference)
//
#include <hip/hip_runtime.h>

#define BATCH 8
#define NNP 10240     // LDS array capacity (>= N=10000)
#define NPB 125       // nodes per block in pull kernels (N/NPB = 80 blocks)

__global__ void fx_kernel(const float* __restrict__ values,
                          float* __restrict__ fx, int bn) {
    int i = blockIdx.x * blockDim.x + threadIdx.x;
    if (i < bn) fx[i] = tanhf(values[i]);
}

// ---------- CSR build ----------
// dir z=0: rows = tgt (idx row 1), payload = src (idx row 0)   [phase 1]
// dir z=1: rows = src (idx row 0), payload = tgt (idx row 1)   [phase 2]

// B1: per-chunk histogram of row indices -> ushort hist[z][k][t]
__global__ __launch_bounds__(1024) void hist_kernel(
        const int* __restrict__ idx, unsigned short* __restrict__ hist,
        int E, int N, int chunk, int K)
{
    __shared__ int cnt[NNP];
    for (int i = threadIdx.x; i < N; i += 1024) cnt[i] = 0;
    __syncthreads();

    const int k = blockIdx.x, z = blockIdx.y;
    const int* tp = idx + (z == 0 ? (long)E : 0L);
    long e0 = (long)k * chunk, e1 = e0 + chunk;
    if (e1 > E) e1 = E;
    long n = e1 - e0, nv = n >> 2;
    const int4* t4p = (const int4*)(tp + e0);
    for (long v = threadIdx.x; v < nv; v += 1024) {
        int4 t4 = t4p[v];
        atomicAdd(&cnt[t4.x], 1); atomicAdd(&cnt[t4.y], 1);
        atomicAdd(&cnt[t4.z], 1); atomicAdd(&cnt[t4.w], 1);
    }
    for (long e = (nv << 2) + threadIdx.x; e < n; e += 1024)
        atomicAdd(&cnt[tp[e0 + e]], 1);
    __syncthreads();

    unsigned short* hp = hist + ((long)z * K + k) * N;
    for (int i = threadIdx.x; i < N; i += 1024) hp[i] = (unsigned short)cnt[i];
}

// B2a: colsum[z][t] = sum_k hist[z][k][t]  (written into rs slots)
__global__ void colsum_kernel(const unsigned short* __restrict__ hist,
                              int* __restrict__ rs, int N, int K)
{
    int z = blockIdx.y;
    int t = blockIdx.x * 256 + threadIdx.x;
    if (t >= N) return;
    const unsigned short* h = hist + (long)z * K * N + t;
    int s = 0;
    for (int k = 0; k < K; ++k) s += h[(long)k * N];
    rs[(long)z * (N + 1) + t] = s;
}

// B2b: in-place exclusive scan of rs[z][0..N) -> row_start; rs[z][N] = total
__global__ __launch_bounds__(1024) void scan_kernel(int* __restrict__ rs, int N)
{
    __shared__ int csum[NNP];
    __shared__ int wtot[16];
    const int z = blockIdx.x;
    int* a = rs + (long)z * (N + 1);
    const int tid = threadIdx.x;
    for (int i = tid; i < N; i += 1024) csum[i] = a[i];
    for (int i = N + tid; i < NNP; i += 1024) csum[i] = 0;
    __syncthreads();

    const int CPT = NNP / 1024;   // 10
    int t0 = tid * CPT;
    int s = 0;
#pragma unroll
    for (int j = 0; j < CPT; ++j) s += csum[t0 + j];

    int lane = tid & 63, wid = tid >> 6;
    int v = s;
#pragma unroll
    for (int off = 1; off < 64; off <<= 1) {
        int u = __shfl_up(v, off, 64);
        if (lane >= off) v += u;
    }
    if (lane == 63) wtot[wid] = v;
    __syncthreads();
    if (wid == 0 && lane < 16) {
        int wv = wtot[lane];
#pragma unroll
        for (int off = 1; off < 16; off <<= 1) {
            int u = __shfl_up(wv, off, 64);
            if (lane >= off) wv += u;
        }
        wtot[lane] = wv;
    }
    __syncthreads();

    int run = (v - s) + (wid ? wtot[wid - 1] : 0);   // exclusive prefix
#pragma unroll
    for (int j = 0; j < CPT; ++j) {
        int t = t0 + j;
        int c = csum[t];
        if (t < N) a[t] = run;
        run += c;
    }
    if (tid == 1023) a[N] = run;   // total == E
}

// B3: in-place transform hist counts -> k-exclusive prefix (per-row rel base)
__global__ void relbase_kernel(unsigned short* __restrict__ hist, int N, int K)
{
    int z = blockIdx.y;
    int t = blockIdx.x * 256 + threadIdx.x;
    if (t >= N) return;
    unsigned short* h = hist + (long)z * K * N + t;
    int run = 0;
    for (int k = 0; k < K; ++k) {
        unsigned short* p = h + (long)k * N;
        int c = *p;
        *p = (unsigned short)run;
        run += c;
    }
}

// B4: place entries: ent[z][row_start[t] + relbase[k][t] + local_rank] = {payload, w}
__global__ __launch_bounds__(1024) void place_kernel(
        const int* __restrict__ idx, const float* __restrict__ w,
        const int* __restrict__ rs, const unsigned short* __restrict__ rel,
        int2* __restrict__ ent, int E, int N, int chunk, int K)
{
    __shared__ int cur[NNP];
    const int k = blockIdx.x, z = blockIdx.y;
    const int* rsz = rs + (long)z * (N + 1);
    const unsigned short* rl = rel + ((long)z * K + k) * N;
    for (int i = threadIdx.x; i < N; i += 1024) cur[i] = rsz[i] + (int)rl[i];
    __syncthreads();

    const int* tp = idx + (z == 0 ? (long)E : 0L);
    const int* gp = idx + (z == 0 ? 0L : (long)E);
    int2* eo = ent + (long)z * E;
    long e0 = (long)k * chunk, e1 = e0 + chunk;
    if (e1 > E) e1 = E;
    long n = e1 - e0, nv = n >> 2;
    const int4*   t4p = (const int4*)(tp + e0);
    const int4*   g4p = (const int4*)(gp + e0);
    const float4* w4p = (const float4*)(w + e0);
    for (long v = threadIdx.x; v < nv; v += 1024) {
        int4 t4 = t4p[v]; int4 g4 = g4p[v]; float4 w4 = w4p[v];
        int p0 = atomicAdd(&cur[t4.x], 1); eo[p0] = make_int2(g4.x, __float_as_int(w4.x));
        int p1 = atomicAdd(&cur[t4.y], 1); eo[p1] = make_int2(g4.y, __float_as_int(w4.y));
        int p2 = atomicAdd(&cur[t4.z], 1); eo[p2] = make_int2(g4.z, __float_as_int(w4.z));
        int p3 = atomicAdd(&cur[t4.w], 1); eo[p3] = make_int2(g4.w, __float_as_int(w4.w));
    }
    for (long e = (nv << 2) + threadIdx.x; e < n; e += 1024) {
        int t = tp[e0 + e];
        int p = atomicAdd(&cur[t], 1);
        eo[p] = make_int2(gp[e0 + e], __float_as_int(w[e0 + e]));
    }
}

// ---------- pull phases (no atomics; wave per node, coalesced entry reads) ----------

// P1: pred[b,t] = sum_{e in row t} w_e * fx[b, src_e];  err = values - pred
__global__ __launch_bounds__(256) void pull_pred_kernel(
        const float* __restrict__ values, const float* __restrict__ fx,
        const int* __restrict__ rs, const int2* __restrict__ ent,
        float* __restrict__ pred, float* __restrict__ err, int N)
{
    __shared__ float fxs[NNP];
    const int c = blockIdx.x, b = blockIdx.y;
    const float* fb = fx + (long)b * N;
    int n4 = N >> 2;
    for (int i = threadIdx.x; i < n4; i += 256) ((float4*)fxs)[i] = ((const float4*)fb)[i];
    for (int i = (n4 << 2) + threadIdx.x; i < N; i += 256) fxs[i] = fb[i];
    __syncthreads();

    const int wid = threadIdx.x >> 6, lane = threadIdx.x & 63;
    for (int nn = wid; nn < NPB; nn += 4) {
        int t = c * NPB + nn;
        if (t >= N) break;
        int s0 = rs[t], s1 = rs[t + 1];
        float acc = 0.0f;
        for (int e = s0 + lane; e < s1; e += 64) {
            int2 E2 = ent[e];
            acc += __int_as_float(E2.y) * fxs[E2.x];
        }
#pragma unroll
        for (int off = 32; off; off >>= 1) acc += __shfl_down(acc, off, 64);
        if (lane == 0) {
            long j = (long)b * N + t;
            pred[j] = acc;
            err[j] = values[j] - acc;
        }
    }
}

// P2: aggr[b,s] = sum_{e in row s} w_e * err[b, tgt_e]; dx = err - (1-fx^2)*aggr
__global__ __launch_bounds__(256) void pull_dx_kernel(
        const float* __restrict__ fx, const float* __restrict__ err,
        const int* __restrict__ rs, const int2* __restrict__ ent,
        float* __restrict__ dx, int N)
{
    __shared__ float es[NNP];
    const int c = blockIdx.x, b = blockIdx.y;
    const float* eb = err + (long)b * N;
    int n4 = N >> 2;
    for (int i = threadIdx.x; i < n4; i += 256) ((float4*)es)[i] = ((const float4*)eb)[i];
    for (int i = (n4 << 2) + threadIdx.x; i < N; i += 256) es[i] = eb[i];
    __syncthreads();

    const int wid = threadIdx.x >> 6, lane = threadIdx.x & 63;
    for (int nn = wid; nn < NPB; nn += 4) {
        int t = c * NPB + nn;
        if (t >= N) break;
        int s0 = rs[t], s1 = rs[t + 1];
        float acc = 0.0f;
        for (int e = s0 + lane; e < s1; e += 64) {
            int2 E2 = ent[e];
            acc += __int_as_float(E2.y) * es[E2.x];
        }
#pragma unroll
        for (int off = 32; off; off >>= 1) acc += __shfl_down(acc, off, 64);
        if (lane == 0) {
            long j = (long)b * N + t;
            float f = fx[j];
            dx[j] = err[j] - (1.0f - f * f) * acc;
        }
    }
}

extern "C" void kernel_launch(void* const* d_in, const int* in_sizes, int n_in,
                              void* d_out, int out_size, void* d_ws, size_t ws_size,
                              hipStream_t stream) {
    const float* values  = (const float*)d_in[0];   // [B*N]
    const float* weights = (const float*)d_in[1];   // [E]
    const int*   edge_ix = (const int*)d_in[2];     // [2, E] (int32 on device)

    const int BN = in_sizes[0];        // 80000
    const int E  = in_sizes[1];        // 2,000,000
    const int N  = BN / BATCH;         // 10000

    float* out  = (float*)d_out;       // [3, B*N]
    float* pred = out;
    float* err  = out + BN;
    float* dx   = out + 2 * BN;

    // workspace layout (16B-aligned slabs)
    auto align16 = [](size_t x) { return (x + 15) & ~(size_t)15; };
    char* ws = (char*)d_ws;
    size_t off = 0;
    float* fx = (float*)(ws + off);                 off += align16((size_t)BN * 4);
    int*   rs = (int*)(ws + off);                   off += align16((size_t)2 * (N + 1) * 4);

    // choose K (edge chunks) so everything fits; K>=128 keeps all CUs busy
    int K = 128;
    size_t hist_off, ent_off, need;
    for (;;) {
        hist_off = off;
        size_t h = align16((size_t)2 * K * N * 2);          // ushort hist
        ent_off  = hist_off + h;
        need     = ent_off + (size_t)2 * E * 8;             // int2 entries
        if (need <= ws_size || K <= 16) break;
        K >>= 1;
    }
    unsigned short* hist = (unsigned short*)(ws + hist_off);
    int2*           ent  = (int2*)(ws + ent_off);

    int chunk = (((E + K - 1) / K) + 3) & ~3;
    int Kused = (E + chunk - 1) / chunk;

    fx_kernel<<<(BN + 255) / 256, 256, 0, stream>>>(values, fx, BN);

    dim3 bgrid(Kused, 2);
    dim3 ngrid((N + 255) / 256, 2);
    hist_kernel<<<bgrid, 1024, 0, stream>>>(edge_ix, hist, E, N, chunk, Kused);
    colsum_kernel<<<ngrid, 256, 0, stream>>>(hist, rs, N, Kused);
    scan_kernel<<<2, 1024, 0, stream>>>(rs, N);
    relbase_kernel<<<ngrid, 256, 0, stream>>>(hist, N, Kused);
    place_kernel<<<bgrid, 1024, 0, stream>>>(edge_ix, weights, rs, hist, ent,
                                             E, N, chunk, Kused);

    dim3 pgrid((N + NPB - 1) / NPB, BATCH);
    pull_pred_kernel<<<pgrid, 256, 0, stream>>>(values, fx, rs, ent, pred, err, N);
    pull_dx_kernel<<<pgrid, 256, 0, stream>>>(fx, err, rs + (N + 1), ent + E, dx, N);
}

// Round 7
// 182.467 us; speedup vs baseline: 1.6057x; 1.6057x over previous
//
#include <hip/hip_runtime.h>

#define BATCH 8
#define NN 10000      // nodes per graph (N)
#define STB 1024      // scatter block size (16 waves)

typedef _Float16 h2 __attribute__((ext_vector_type(2)));

// Packed 2xf16 LDS atomic add (ds_pk_add_f16): one atomic covers TWO batches.
__device__ __forceinline__ void lds_pk_add(h2* p, h2 v) {
#if __has_builtin(__builtin_amdgcn_ds_atomic_fadd_v2f16)
    __builtin_amdgcn_ds_atomic_fadd_v2f16(
        (__attribute__((address_space(3))) h2*)p, v);
#else
    asm volatile("ds_pk_add_f16 %0, %1"
                 :: "v"((unsigned)(unsigned long long)p), "v"(v)
                 : "memory");
#endif
}

// ---------------- scatter phase 1 ----------------
// block = (chunk k, batch-pair bp). Stage fx = tanh(values) for batches
// (2bp, 2bp+1) as packed f16; accumulate msg = w * fx into h2 LDS accumulator
// with ds_pk_add_f16. Flush coalesced.
// partial layout: partial[(k*4+bp)*N + t]  (h2)
__global__ __launch_bounds__(STB, 8) void scatter1_kernel(
        const float* __restrict__ values,
        const float* __restrict__ w,
        const int* __restrict__ idx,
        h2* __restrict__ partial,
        int E, int N, int chunk)
{
    __shared__ alignas(16) h2 acc2[NN];
    __shared__ alignas(16) h2 fxs2[NN];
    const int k = blockIdx.x, bp = blockIdx.y;
    const float* __restrict__ v0 = values + (long)(2 * bp) * N;
    const float* __restrict__ v1 = values + (long)(2 * bp + 1) * N;

    int n4 = N >> 2;                       // N%4==0
    int4* az = (int4*)acc2;
    for (int i = threadIdx.x; i < n4; i += STB) az[i] = make_int4(0, 0, 0, 0);
    for (int i = threadIdx.x; i < N; i += STB) {
        h2 f = { (_Float16)tanhf(v0[i]), (_Float16)tanhf(v1[i]) };
        fxs2[i] = f;
    }
    __syncthreads();

    long e0 = (long)k * chunk, e1 = e0 + chunk;
    if (e1 > E) e1 = E;
    long n = e1 - e0, nv = n >> 2;
    const int4*   g4p = (const int4*)(idx + e0);           // src row 0: gather
    const int4*   s4p = (const int4*)(idx + (long)E + e0); // tgt row 1: scatter
    const float4* w4p = (const float4*)(w + e0);

    for (long v = threadIdx.x; v < nv; v += STB) {
        int4 gi = g4p[v]; int4 si = s4p[v]; float4 wv = w4p[v];
        h2 w0 = { (_Float16)wv.x, (_Float16)wv.x };
        h2 w1 = { (_Float16)wv.y, (_Float16)wv.y };
        h2 w2 = { (_Float16)wv.z, (_Float16)wv.z };
        h2 w3 = { (_Float16)wv.w, (_Float16)wv.w };
        h2 m0 = w0 * fxs2[gi.x];
        h2 m1 = w1 * fxs2[gi.y];
        h2 m2 = w2 * fxs2[gi.z];
        h2 m3 = w3 * fxs2[gi.w];
        lds_pk_add(&acc2[si.x], m0);
        lds_pk_add(&acc2[si.y], m1);
        lds_pk_add(&acc2[si.z], m2);
        lds_pk_add(&acc2[si.w], m3);
    }
    for (long e = (nv << 2) + threadIdx.x; e < n; e += STB) {
        int gi = idx[e0 + e], si = idx[(long)E + e0 + e];
        _Float16 wf = (_Float16)w[e0 + e];
        h2 wb = { wf, wf };
        lds_pk_add(&acc2[si], wb * fxs2[gi]);
    }
    __syncthreads();

    int4* pz = (int4*)(partial + ((long)k * 4 + bp) * N);
    for (int i = threadIdx.x; i < n4; i += STB) pz[i] = az[i];
}

// ---------------- scatter phase 2 ----------------
// gather err at tgt, scatter to src. err staged from packed err2.
__global__ __launch_bounds__(STB, 8) void scatter2_kernel(
        const h2* __restrict__ err2,   // [4][N] h2 (per batch-pair)
        const float* __restrict__ w,
        const int* __restrict__ idx,
        h2* __restrict__ partial,
        int E, int N, int chunk)
{
    __shared__ alignas(16) h2 acc2[NN];
    __shared__ alignas(16) h2 es2[NN];
    const int k = blockIdx.x, bp = blockIdx.y;

    int n4 = N >> 2;
    int4* az = (int4*)acc2;
    int4* ez = (int4*)es2;
    const int4* e4 = (const int4*)(err2 + (long)bp * N);
    for (int i = threadIdx.x; i < n4; i += STB) {
        az[i] = make_int4(0, 0, 0, 0);
        ez[i] = e4[i];
    }
    __syncthreads();

    long e0 = (long)k * chunk, e1 = e0 + chunk;
    if (e1 > E) e1 = E;
    long n = e1 - e0, nv = n >> 2;
    const int4*   g4p = (const int4*)(idx + (long)E + e0);  // tgt row 1: gather
    const int4*   s4p = (const int4*)(idx + e0);            // src row 0: scatter
    const float4* w4p = (const float4*)(w + e0);

    for (long v = threadIdx.x; v < nv; v += STB) {
        int4 gi = g4p[v]; int4 si = s4p[v]; float4 wv = w4p[v];
        h2 w0 = { (_Float16)wv.x, (_Float16)wv.x };
        h2 w1 = { (_Float16)wv.y, (_Float16)wv.y };
        h2 w2 = { (_Float16)wv.z, (_Float16)wv.z };
        h2 w3 = { (_Float16)wv.w, (_Float16)wv.w };
        h2 m0 = w0 * es2[gi.x];
        h2 m1 = w1 * es2[gi.y];
        h2 m2 = w2 * es2[gi.z];
        h2 m3 = w3 * es2[gi.w];
        lds_pk_add(&acc2[si.x], m0);
        lds_pk_add(&acc2[si.y], m1);
        lds_pk_add(&acc2[si.z], m2);
        lds_pk_add(&acc2[si.w], m3);
    }
    for (long e = (nv << 2) + threadIdx.x; e < n; e += STB) {
        int gi = idx[(long)E + e0 + e], si = idx[e0 + e];
        _Float16 wf = (_Float16)w[e0 + e];
        h2 wb = { wf, wf };
        lds_pk_add(&acc2[si], wb * es2[gi]);
    }
    __syncthreads();

    int4* pz = (int4*)(partial + ((long)k * 4 + bp) * N);
    for (int i = threadIdx.x; i < n4; i += STB) pz[i] = az[i];
}

// ---------------- reduce 1: pred, err, err2 ----------------
// block (64 t-lanes x 8 k-groups); fp32 cross-chunk reduction.
__global__ __launch_bounds__(512) void reduce1_kernel(
        const h2* __restrict__ partial,
        const float* __restrict__ values,
        float* __restrict__ pred, float* __restrict__ err,
        h2* __restrict__ err2, int N, int K)
{
    __shared__ float2 sm[8][64];
    const int l = threadIdx.x, g = threadIdx.y;
    const int t = blockIdx.x * 64 + l, bp = blockIdx.y;
    float2 s = {0.f, 0.f};
    if (t < N) {
        const h2* p = partial + (long)bp * N + t;
        for (int k = g; k < K; k += 8) {
            h2 v = p[(long)k * 4 * N];
            s.x += (float)v.x; s.y += (float)v.y;
        }
    }
    sm[g][l] = s;
    __syncthreads();
    if (g == 0 && t < N) {
        float2 a = sm[0][l];
#pragma unroll
        for (int r = 1; r < 8; ++r) { a.x += sm[r][l].x; a.y += sm[r][l].y; }
        long j0 = (long)(2 * bp) * N + t, j1 = j0 + N;
        float e0 = values[j0] - a.x, e1 = values[j1] - a.y;
        pred[j0] = a.x; pred[j1] = a.y;
        err[j0] = e0;   err[j1] = e1;
        h2 ep = { (_Float16)e0, (_Float16)e1 };
        err2[(long)bp * N + t] = ep;
    }
}

// ---------------- reduce 2: dx = err - (1 - fx^2) * aggr ----------------
__global__ __launch_bounds__(512) void reduce2_kernel(
        const h2* __restrict__ partial,
        const float* __restrict__ values,
        const float* __restrict__ err,
        float* __restrict__ dx, int N, int K)
{
    __shared__ float2 sm[8][64];
    const int l = threadIdx.x, g = threadIdx.y;
    const int t = blockIdx.x * 64 + l, bp = blockIdx.y;
    float2 s = {0.f, 0.f};
    if (t < N) {
        const h2* p = partial + (long)bp * N + t;
        for (int k = g; k < K; k += 8) {
            h2 v = p[(long)k * 4 * N];
            s.x += (float)v.x; s.y += (float)v.y;
        }
    }
    sm[g][l] = s;
    __syncthreads();
    if (g == 0 && t < N) {
        float2 a = sm[0][l];
#pragma unroll
        for (int r = 1; r < 8; ++r) { a.x += sm[r][l].x; a.y += sm[r][l].y; }
        long j0 = (long)(2 * bp) * N + t, j1 = j0 + N;
        float f0 = tanhf(values[j0]), f1 = tanhf(values[j1]);
        dx[j0] = err[j0] - (1.0f - f0 * f0) * a.x;
        dx[j1] = err[j1] - (1.0f - f1 * f1) * a.y;
    }
}

extern "C" void kernel_launch(void* const* d_in, const int* in_sizes, int n_in,
                              void* d_out, int out_size, void* d_ws, size_t ws_size,
                              hipStream_t stream) {
    const float* values  = (const float*)d_in[0];   // [B*N]
    const float* weights = (const float*)d_in[1];   // [E]
    const int*   edge_ix = (const int*)d_in[2];     // [2, E]

    const int BN = in_sizes[0];        // 80000
    const int E  = in_sizes[1];        // 2,000,000
    const int N  = BN / BATCH;         // 10000

    float* out  = (float*)d_out;       // [3, B*N]
    float* pred = out;
    float* err  = out + BN;
    float* dx   = out + 2 * BN;

    // workspace: err2 [4][N] h2, partial [K][4][N] h2
    auto align16 = [](size_t x) { return (x + 15) & ~(size_t)15; };
    char* ws = (char*)d_ws;
    h2* err2 = (h2*)ws;
    size_t off = align16((size_t)4 * N * sizeof(h2));
    int K = 128;
    while (K > 16 && off + (size_t)K * 4 * N * sizeof(h2) > ws_size) K >>= 1;
    h2* partial = (h2*)(ws + off);

    int chunk = (((E + K - 1) / K) + 3) & ~3;
    int Kused = (E + chunk - 1) / chunk;

    dim3 sgrid(Kused, 4);                 // 4 batch-pairs
    dim3 rgrid((N + 63) / 64, 4);
    dim3 rblock(64, 8);

    scatter1_kernel<<<sgrid, STB, 0, stream>>>(values, weights, edge_ix,
                                               partial, E, N, chunk);
    reduce1_kernel<<<rgrid, rblock, 0, stream>>>(partial, values, pred, err,
                                                 err2, N, Kused);
    scatter2_kernel<<<sgrid, STB, 0, stream>>>(err2, weights, edge_ix,
                                               partial, E, N, chunk);
    reduce2_kernel<<<rgrid, rblock, 0, stream>>>(partial, values, err, dx,
                                                 N, Kused);
}